// Round 9
// baseline (550.599 us; speedup 1.0000x reference)
//
#include <hip/hip_runtime.h>
#include <hip/hip_fp16.h>

#define N_NODES 100000
#define N_EDGES 1600000
#define D 128
#define SCAN_NB ((N_NODES + 1023) / 1024)   // 98
#define CHK 128                             // edge chunks
#define CHUNK_E (N_EDGES / CHK)             // 12500 edges/chunk
#define HALF_N 50000                        // hist: nodes per half
#define HALF_U (HALF_N / 4)                 // 12500 uints (8-bit packed, 50 KB LDS)
#define PP_STRIDE (N_NODES / 4)             // 25000 uints per (arr,chunk)
#define NSH2 2                              // scatter shards
#define SH2 (N_NODES / NSH2)                // 50000 nodes/shard
#define SH2_U (SH2 / 4)                     // 12500 uints (50 KB LDS)
#define PADH 136                            // LDS row stride in halves (272 B, 16B-aligned)

typedef _Float16 f16x4 __attribute__((ext_vector_type(4)));
typedef _Float16 f16x8 __attribute__((ext_vector_type(8)));
typedef float f32x4 __attribute__((ext_vector_type(4)));
typedef float f32x2 __attribute__((ext_vector_type(2)));

// ---------------------------------------------------------------------------
// Pass A: LDS histograms, 8-bit packed (4 nodes/uint). block=(arr,half,chunk).
__global__ __launch_bounds__(256) void
k_hist(const int* __restrict__ src, const int* __restrict__ dst,
       unsigned int* __restrict__ pp) {
    __shared__ unsigned int h[HALF_U];  // 50 KB
    int b = blockIdx.x;
    int arr = b >> 8, half = (b >> 7) & 1, c = b & (CHK - 1);
    const int* a = arr ? dst : src;
    int lo = half * HALF_N;
    for (int i = threadIdx.x; i < HALF_U; i += 256) h[i] = 0;
    __syncthreads();
    int e0 = c * CHUNK_E;
    for (int i = e0 + threadIdx.x; i < e0 + CHUNK_E; i += 256) {
        int v = a[i] - lo;
        if ((unsigned)v < HALF_N)
            atomicAdd(&h[v >> 2], 1u << ((v & 3) * 8));
    }
    __syncthreads();
    unsigned int* po = pp + ((size_t)(arr * CHK + c)) * PP_STRIDE + half * HALF_U;
    for (int i = threadIdx.x; i < HALF_U; i += 256) po[i] = h[i];
}

// Pass B: totals -> cnt; partials -> exclusive per-chunk prefix (8-bit), in place.
__global__ void k_merge(unsigned int* __restrict__ pp,
                        int* __restrict__ cnt_src, int* __restrict__ cnt_dst) {
    int g = blockIdx.x * blockDim.x + threadIdx.x;
    if (g >= 2 * PP_STRIDE) return;
    int arr = g / PP_STRIDE, u = g % PP_STRIDE;
    unsigned int* p = pp + ((size_t)arr * CHK) * PP_STRIDE + u;
    int s0 = 0, s1 = 0, s2 = 0, s3 = 0;
#pragma unroll 8
    for (int c = 0; c < CHK; c++) {
        unsigned int v = p[(size_t)c * PP_STRIDE];
        p[(size_t)c * PP_STRIDE] =
            (unsigned)s0 | ((unsigned)s1 << 8) | ((unsigned)s2 << 16) | ((unsigned)s3 << 24);
        s0 += v & 255; s1 += (v >> 8) & 255; s2 += (v >> 16) & 255; s3 += (v >> 24) & 255;
    }
    int* cnt = arr ? cnt_dst : cnt_src;
    cnt[4 * u + 0] = s0; cnt[4 * u + 1] = s1; cnt[4 * u + 2] = s2; cnt[4 * u + 3] = s3;
}

// scan both cnt arrays
__global__ __launch_bounds__(1024) void
k_scan1(const int* __restrict__ cnt_dst, const int* __restrict__ cnt_src,
        int* __restrict__ rpD, int* __restrict__ rpS,
        int* __restrict__ bsD, int* __restrict__ bsS) {
    __shared__ int s[1024];
    int arr = blockIdx.x / SCAN_NB, bb = blockIdx.x % SCAN_NB;
    const int* cnt = arr ? cnt_src : cnt_dst;
    int* rp1 = (arr ? rpS : rpD) + 1;
    int* bs = arr ? bsS : bsD;
    int tid = threadIdx.x;
    int i = bb * 1024 + tid;
    int v = (i < N_NODES) ? cnt[i] : 0;
    s[tid] = v;
    __syncthreads();
    for (int d = 1; d < 1024; d <<= 1) {
        int t = (tid >= d) ? s[tid - d] : 0;
        __syncthreads();
        s[tid] += t;
        __syncthreads();
    }
    if (i < N_NODES) rp1[i] = s[tid];
    if (tid == 1023) bs[bb] = s[1023];
}

__global__ void k_scan2(int* __restrict__ bsD, int* __restrict__ bsS) {
    __shared__ int s[128];
    int* bs = blockIdx.x ? bsS : bsD;
    int tid = threadIdx.x;
    int v = (tid < SCAN_NB) ? bs[tid] : 0;
    s[tid] = v;
    __syncthreads();
    for (int d = 1; d < 128; d <<= 1) {
        int t = (tid >= d) ? s[tid - d] : 0;
        __syncthreads();
        s[tid] += t;
        __syncthreads();
    }
    if (tid < SCAN_NB) bs[tid] = s[tid] - v;  // exclusive
}

// finalize both row_ptrs + norms + zero colsum
__global__ void k_scan3norm(int* __restrict__ rpD, int* __restrict__ rpS,
                            const int* __restrict__ bsD, const int* __restrict__ bsS,
                            const int* __restrict__ cnt_src, const int* __restrict__ cnt_dst,
                            float* __restrict__ ns, float* __restrict__ nd,
                            float* __restrict__ colsum) {
    int i = blockIdx.x * blockDim.x + threadIdx.x;
    if (i >= N_NODES) return;
    rpD[1 + i] += bsD[i >> 10];
    rpS[1 + i] += bsS[i >> 10];
    if (i == 0) { rpD[0] = 0; rpS[0] = 0; }
    if (i < 128) colsum[i] = 0.0f;
    ns[i] = rsqrtf((float)max(cnt_src[i], 1));
    nd[i] = rsqrtf((float)max(cnt_dst[i], 1));
}

// Pass C1: counting-sort by dst, payload src. 2 shards (50 KB LDS, 3 blk/CU).
__global__ __launch_bounds__(256) void
k_scatter_dst(const int* __restrict__ src, const int* __restrict__ dst,
              const int* __restrict__ rpD, const unsigned int* __restrict__ pp,
              int* __restrict__ csr_src) {
    __shared__ unsigned int cur[SH2_U];  // 50 KB
    int sh = blockIdx.x & 1, c = blockIdx.x >> 1;
    int lo = sh * SH2;
    const unsigned int* pre = pp + ((size_t)(CHK + c)) * PP_STRIDE;  // arr=1 (dst)
    for (int i = threadIdx.x; i < SH2_U; i += 256) cur[i] = 0;
    __syncthreads();
    int e0 = c * CHUNK_E;
    for (int i = e0 + threadIdx.x; i < e0 + CHUNK_E; i += 256) {
        int dfull = dst[i];
        int d = dfull - lo;
        if ((unsigned)d < SH2) {
            int sft = (d & 3) * 8;
            int rank = (atomicAdd(&cur[d >> 2], 1u << sft) >> sft) & 255;
            int p8 = (pre[dfull >> 2] >> ((dfull & 3) * 8)) & 255;
            csr_src[rpD[dfull] + p8 + rank] = src[i];
        }
    }
}

// Pass C2: counting-sort by src, payload nd[dst] -> csrv.
__global__ __launch_bounds__(256) void
k_scatter_src(const int* __restrict__ src, const int* __restrict__ dst,
              const int* __restrict__ rpS, const unsigned int* __restrict__ pp,
              const float* __restrict__ nd, float* __restrict__ csrv) {
    __shared__ unsigned int cur[SH2_U];  // 50 KB
    int sh = blockIdx.x & 1, c = blockIdx.x >> 1;
    int lo = sh * SH2;
    const unsigned int* pre = pp + (size_t)c * PP_STRIDE;  // arr=0 (src)
    for (int i = threadIdx.x; i < SH2_U; i += 256) cur[i] = 0;
    __syncthreads();
    int e0 = c * CHUNK_E;
    for (int i = e0 + threadIdx.x; i < e0 + CHUNK_E; i += 256) {
        int sfull = src[i];
        int s = sfull - lo;
        if ((unsigned)s < SH2) {
            int sft = (s & 3) * 8;
            int rank = (atomicAdd(&cur[s >> 2], 1u << sft) >> sft) & 255;
            int p8 = (pre[sfull >> 2] >> ((sfull & 3) * 8)) & 255;
            csrv[rpS[sfull] + p8 + rank] = nd[dst[i]];
        }
    }
}

// wsum[n] = ns[n] * sum of csrv over n's src-list
__global__ void k_wsum(const int* __restrict__ rpS, const float* __restrict__ csrv,
                       const float* __restrict__ ns, float* __restrict__ wsum) {
    int gid = blockIdx.x * blockDim.x + threadIdx.x;
    int wv = gid >> 6, lane = gid & 63;
    int n = wv * 16 + (lane & 15);
    int off = lane >> 4;
    float s = 0.0f;
    int beg = 0, end = 0;
    if (n < N_NODES) { beg = rpS[n]; end = rpS[n + 1]; }
    for (int j = beg + off; j < end; j += 4) s += csrv[j];
    s += __shfl_xor(s, 16, 64);
    s += __shfl_xor(s, 32, 64);
    if (n < N_NODES && lane < 16) wsum[n] = s * ns[n];
}

// fused prep: blocks [0,128): Wt16[l][n][k] = half(Wl[k][n]);
//             blocks [128,...): x8[n][:] = fp8(h[n][:] * ns[n])
__global__ void k_prep(const float* __restrict__ W0, const float* __restrict__ W1,
                       __half* __restrict__ Wt, const float* __restrict__ x,
                       const float* __restrict__ ns, unsigned int* __restrict__ out) {
    if (blockIdx.x < 128) {
        int i = blockIdx.x * 256 + threadIdx.x;  // over 2*D*D
        int l = i >> 14, r = i & (D * D - 1);
        int n = r >> 7, k = r & 127;
        const float* W = l ? W1 : W0;
        Wt[i] = __float2half(W[k * D + n]);
        return;
    }
    int i = (blockIdx.x - 128) * 256 + threadIdx.x;  // over N*D/4
    if (i >= N_NODES * (D / 4)) return;
    int n = i >> 5;
    float4 v = ((const float4*)x)[i];
    float s = ns[n];
    int u = __builtin_amdgcn_cvt_pk_fp8_f32(v.x * s, v.y * s, 0, false);
    u = __builtin_amdgcn_cvt_pk_fp8_f32(v.z * s, v.w * s, u, true);
    out[i] = (unsigned int)u;
}

// --------------------------------------------------------------------------
// Fused layer kernel core: gather 128 rows (fp8, wave per row, 2 edges/instr)
// -> LDS fp16 (padded rows, 16B-aligned) -> MFMA 128x128x128.
// MODE 0: epilogue writes fp8 rows (relu(nd*acc+b)*ns) to out8.
// MODE 1: epilogue reduces wsum[n]*relu(nd*acc+b) into colsum (no row stores).
template <int MODE>
__device__ void fused_layer(const unsigned char* __restrict__ x8,
                            const int* __restrict__ rpD, const int* __restrict__ csr_src,
                            const __half* __restrict__ Wt, const float* __restrict__ b,
                            const float* __restrict__ nd, const float* __restrict__ ns_or_w,
                            unsigned char* __restrict__ out8, float* __restrict__ colsum,
                            _Float16* As, float* red) {
    int tid = threadIdx.x;
    int w = tid >> 6, lane = tid & 63;
    int hf = lane >> 5, l32 = lane & 31;
    int row0 = blockIdx.x * 128;
    if (MODE == 1 && tid < 128) red[tid] = 0.0f;

    // ---- gather phase: wave w handles rows row0 + w*32 .. +31 ----
    for (int rr = 0; rr < 32; rr++) {
        int node = row0 + w * 32 + rr;
        float a0 = 0.f, a1 = 0.f, a2 = 0.f, a3 = 0.f;
        if (node < N_NODES) {
            int beg = rpD[node], end = rpD[node + 1];
            int j = beg;
            for (; j + 7 < end; j += 8) {
#pragma unroll
                for (int p = 0; p < 4; p++) {
                    int s0 = csr_src[j + 2 * p];
                    int s1 = csr_src[j + 2 * p + 1];
                    int s = hf ? s1 : s0;
                    unsigned int u = *(const unsigned int*)(x8 + (size_t)s * D + 4 * l32);
                    f32x2 lo = __builtin_amdgcn_cvt_pk_f32_fp8(u, false);
                    f32x2 hi = __builtin_amdgcn_cvt_pk_f32_fp8(u, true);
                    a0 += lo[0]; a1 += lo[1]; a2 += hi[0]; a3 += hi[1];
                }
            }
            for (; j + 1 < end; j += 2) {
                int s0 = csr_src[j], s1 = csr_src[j + 1];
                int s = hf ? s1 : s0;
                unsigned int u = *(const unsigned int*)(x8 + (size_t)s * D + 4 * l32);
                f32x2 lo = __builtin_amdgcn_cvt_pk_f32_fp8(u, false);
                f32x2 hi = __builtin_amdgcn_cvt_pk_f32_fp8(u, true);
                a0 += lo[0]; a1 += lo[1]; a2 += hi[0]; a3 += hi[1];
            }
            if (j < end && hf == 0) {
                int s = csr_src[j];
                unsigned int u = *(const unsigned int*)(x8 + (size_t)s * D + 4 * l32);
                f32x2 lo = __builtin_amdgcn_cvt_pk_f32_fp8(u, false);
                f32x2 hi = __builtin_amdgcn_cvt_pk_f32_fp8(u, true);
                a0 += lo[0]; a1 += lo[1]; a2 += hi[0]; a3 += hi[1];
            }
        }
        a0 += __shfl_xor(a0, 32, 64);
        a1 += __shfl_xor(a1, 32, 64);
        a2 += __shfl_xor(a2, 32, 64);
        a3 += __shfl_xor(a3, 32, 64);
        if (hf == 0) {
            f16x4 o;
            o[0] = (_Float16)a0; o[1] = (_Float16)a1; o[2] = (_Float16)a2; o[3] = (_Float16)a3;
            *(f16x4*)(As + (size_t)(w * 32 + rr) * PADH + l32 * 4) = o;
        }
    }
    __syncthreads();

    // ---- MFMA phase: wave w computes its 32 rows x 128 cols ----
    int m = lane & 15, q = lane >> 4;
    const f16x8* pb = (const f16x8*)Wt;
    f32x4 acc[2][8];
#pragma unroll
    for (int g = 0; g < 2; g++)
#pragma unroll
        for (int nt = 0; nt < 8; nt++) acc[g][nt] = (f32x4){0.f, 0.f, 0.f, 0.f};

#pragma unroll
    for (int ks = 0; ks < 4; ks++) {
        f16x8 a0f = *(const f16x8*)(As + (size_t)(w * 32 + m) * PADH + ks * 32 + q * 8);
        f16x8 a1f = *(const f16x8*)(As + (size_t)(w * 32 + 16 + m) * PADH + ks * 32 + q * 8);
#pragma unroll
        for (int nt = 0; nt < 8; nt++) {
            f16x8 bf = pb[((nt * 16 + m) << 4) + (ks << 2) + q];
            acc[0][nt] = __builtin_amdgcn_mfma_f32_16x16x32_f16(a0f, bf, acc[0][nt], 0, 0, 0);
            acc[1][nt] = __builtin_amdgcn_mfma_f32_16x16x32_f16(a1f, bf, acc[1][nt], 0, 0, 0);
        }
    }

    // ---- epilogue: D layout col=lane&15, row=q*4+reg ----
    if (MODE == 0) {
#pragma unroll
        for (int g = 0; g < 2; g++) {
            int er = row0 + w * 32 + g * 16 + q * 4;
            float sd[4], ss[4];
#pragma unroll
            for (int r = 0; r < 4; r++) {
                int n = er + r;
                bool ok = n < N_NODES;
                sd[r] = ok ? nd[n] : 0.0f;
                ss[r] = ok ? ns_or_w[n] : 0.0f;
            }
#pragma unroll
            for (int nt = 0; nt < 8; nt++) {
                int col = nt * 16 + m;
                float bc = b[col];
#pragma unroll
                for (int r = 0; r < 4; r++) {
                    int n = er + r;
                    if (n < N_NODES) {
                        float v = fmaxf(sd[r] * acc[g][nt][r] + bc, 0.0f) * ss[r];
                        int pk = __builtin_amdgcn_cvt_pk_fp8_f32(v, v, 0, false);
                        out8[(size_t)n * D + col] = (unsigned char)(pk & 0xff);
                    }
                }
            }
        }
    } else {
        float sd[2][4], sw[2][4];
#pragma unroll
        for (int g = 0; g < 2; g++) {
            int er = row0 + w * 32 + g * 16 + q * 4;
#pragma unroll
            for (int r = 0; r < 4; r++) {
                int n = er + r;
                bool ok = n < N_NODES;
                sd[g][r] = ok ? nd[n] : 0.0f;
                sw[g][r] = ok ? ns_or_w[n] : 0.0f;  // wsum
            }
        }
#pragma unroll
        for (int nt = 0; nt < 8; nt++) {
            int col = nt * 16 + m;
            float bc = b[col];
            float pc = 0.0f;
#pragma unroll
            for (int g = 0; g < 2; g++)
#pragma unroll
                for (int r = 0; r < 4; r++)
                    pc += sw[g][r] * fmaxf(sd[g][r] * acc[g][nt][r] + bc, 0.0f);
            atomicAdd(&red[col], pc);
        }
        __syncthreads();
        if (tid < 128) unsafeAtomicAdd(&colsum[tid], red[tid]);
    }
}

__global__ __launch_bounds__(256) void
k_fused_l0(const unsigned char* __restrict__ x8, const int* __restrict__ rpD,
           const int* __restrict__ csr_src, const __half* __restrict__ Wt,
           const float* __restrict__ b, const float* __restrict__ nd,
           const float* __restrict__ ns, unsigned char* __restrict__ out8) {
    __shared__ _Float16 As[128 * PADH];  // 34 KB
    fused_layer<0>(x8, rpD, csr_src, Wt, b, nd, ns, out8, nullptr, As, nullptr);
}

__global__ __launch_bounds__(256) void
k_fused_red(const unsigned char* __restrict__ x8, const int* __restrict__ rpD,
            const int* __restrict__ csr_src, const __half* __restrict__ Wt,
            const float* __restrict__ b, const float* __restrict__ nd,
            const float* __restrict__ wsum, float* __restrict__ colsum) {
    __shared__ _Float16 As[128 * PADH];
    __shared__ float red[128];
    fused_layer<1>(x8, rpD, csr_src, Wt, b, nd, wsum, nullptr, colsum, As, red);
}

// out[j] = (colsum/N) @ W2 [:,j] + b2[j]
__global__ void k_final(const float* __restrict__ colsum, const float* __restrict__ W,
                        const float* __restrict__ b, float* __restrict__ out) {
    __shared__ float m[128];
    int j = threadIdx.x;
    m[j] = colsum[j] * (1.0f / N_NODES);
    __syncthreads();
    float acc = b[j];
    for (int k = 0; k < 128; k++)
        acc = fmaf(m[k], W[(size_t)k * D + j], acc);
    out[j] = acc;
}

extern "C" void kernel_launch(void* const* d_in, const int* in_sizes, int n_in,
                              void* d_out, int out_size, void* d_ws, size_t ws_size,
                              hipStream_t stream) {
    const float* h   = (const float*)d_in[0];
    const int*   src = (const int*)d_in[1];
    const int*   dst = (const int*)d_in[2];
    const float* W0  = (const float*)d_in[3];
    const float* b0  = (const float*)d_in[4];
    const float* W1  = (const float*)d_in[5];
    const float* b1  = (const float*)d_in[6];
    const float* W2  = (const float*)d_in[7];
    const float* b2  = (const float*)d_in[8];
    float* out = (float*)d_out;

    // workspace (~42 MB); pp (25.6 MB) dead after scatters -> x8a/x8b alias it
    float*         ns      = (float*)d_ws;                       // N
    float*         nd      = ns + N_NODES;                       // N
    float*         wsum    = nd + N_NODES;                       // N
    float*         colsum  = wsum + N_NODES;                     // 128
    int*           rpD     = (int*)(colsum + 128);               // N+1
    int*           rpS     = rpD + N_NODES + 1;                  // N+1
    int*           cnt_src = rpS + N_NODES + 1;                  // N
    int*           cnt_dst = cnt_src + N_NODES;                  // N
    int*           bsD     = cnt_dst + N_NODES;                  // 128
    int*           bsS     = bsD + 128;                          // 128
    __half*        Wt16    = (__half*)(bsS + 128);               // 2*D*D
    int*           csr_src = (int*)(Wt16 + 2 * D * D);           // E
    float*         csrv    = (float*)(csr_src + N_EDGES);        // E
    unsigned int*  pp      = (unsigned int*)(csrv + N_EDGES);    // 25.6 MB
    unsigned char* x8a     = (unsigned char*)pp;                 // N*D fp8 (12.8 MB)
    unsigned char* x8b     = x8a + (size_t)N_NODES * D;          // N*D fp8 (12.8 MB)

    // ---- CSR build (both directions) + norms + wsum; no global atomics ----
    k_hist<<<2 * 2 * CHK, 256, 0, stream>>>(src, dst, pp);
    k_merge<<<(2 * PP_STRIDE + 255) / 256, 256, 0, stream>>>(pp, cnt_src, cnt_dst);
    k_scan1<<<2 * SCAN_NB, 1024, 0, stream>>>(cnt_dst, cnt_src, rpD, rpS, bsD, bsS);
    k_scan2<<<2, 128, 0, stream>>>(bsD, bsS);
    k_scan3norm<<<(N_NODES + 255) / 256, 256, 0, stream>>>(rpD, rpS, bsD, bsS,
                                                           cnt_src, cnt_dst, ns, nd, colsum);
    k_scatter_dst<<<NSH2 * CHK, 256, 0, stream>>>(src, dst, rpD, pp, csr_src);
    k_scatter_src<<<NSH2 * CHK, 256, 0, stream>>>(src, dst, rpS, pp, nd, csrv);
    k_wsum<<<(N_NODES * 4 + 255) / 256, 256, 0, stream>>>(rpS, csrv, ns, wsum);

    // Wt + x0 = fp8(h*ns)  (x8a overwrites pp region — stream-ordered after scatters)
    k_prep<<<128 + (N_NODES * (D / 4) + 255) / 256, 256, 0, stream>>>(
        W0, W1, Wt16, h, ns, (unsigned int*)x8a);

    // layer 0 (fused spmm+gemm): x8a -> x8b
    k_fused_l0<<<(N_NODES + 127) / 128, 256, 0, stream>>>(x8a, rpD, csr_src, Wt16,
                                                          b0, nd, ns, x8b);
    // layer 1 + fused layer-2 reduction: x8b -> colsum
    k_fused_red<<<(N_NODES + 127) / 128, 256, 0, stream>>>(x8b, rpD, csr_src,
                                                           Wt16 + (size_t)D * D,
                                                           b1, nd, wsum, colsum);
    k_final<<<1, 128, 0, stream>>>(colsum, W2, b2, out);
}

// Round 10
// 428.715 us; speedup vs baseline: 1.2843x; 1.2843x over previous
//
#include <hip/hip_runtime.h>
#include <hip/hip_fp16.h>

#define N_NODES 100000
#define N_EDGES 1600000
#define D 128
#define SCAN_NB ((N_NODES + 1023) / 1024)   // 98
#define CHK 128                             // edge chunks
#define CHUNK_E (N_EDGES / CHK)             // 12500 edges/chunk
#define HALF_N 50000                        // hist: nodes per half
#define HALF_U (HALF_N / 4)                 // 12500 uints (8-bit packed, 50 KB LDS)
#define PP_STRIDE (N_NODES / 4)             // 25000 uints per (arr,chunk)
#define NSH2 2                              // scatter shards
#define SH2 (N_NODES / NSH2)                // 50000 nodes/shard
#define SH2_U (SH2 / 4)                     // 12500 uints (50 KB LDS)

typedef _Float16 f16x4 __attribute__((ext_vector_type(4)));
typedef _Float16 f16x8 __attribute__((ext_vector_type(8)));
typedef float f32x4 __attribute__((ext_vector_type(4)));
typedef float f32x2 __attribute__((ext_vector_type(2)));

// ---------------------------------------------------------------------------
// Pass A: LDS histograms, 8-bit packed (4 nodes/uint). block=(arr,half,chunk).
__global__ __launch_bounds__(256) void
k_hist(const int* __restrict__ src, const int* __restrict__ dst,
       unsigned int* __restrict__ pp) {
    __shared__ unsigned int h[HALF_U];  // 50 KB
    int b = blockIdx.x;
    int arr = b >> 8, half = (b >> 7) & 1, c = b & (CHK - 1);
    const int* a = arr ? dst : src;
    int lo = half * HALF_N;
    for (int i = threadIdx.x; i < HALF_U; i += 256) h[i] = 0;
    __syncthreads();
    int e0 = c * CHUNK_E;
    for (int i = e0 + threadIdx.x; i < e0 + CHUNK_E; i += 256) {
        int v = a[i] - lo;
        if ((unsigned)v < HALF_N)
            atomicAdd(&h[v >> 2], 1u << ((v & 3) * 8));
    }
    __syncthreads();
    unsigned int* po = pp + ((size_t)(arr * CHK + c)) * PP_STRIDE + half * HALF_U;
    for (int i = threadIdx.x; i < HALF_U; i += 256) po[i] = h[i];
}

// Pass B: totals -> cnt; partials -> exclusive per-chunk prefix (8-bit), in place.
__global__ void k_merge(unsigned int* __restrict__ pp,
                        int* __restrict__ cnt_src, int* __restrict__ cnt_dst) {
    int g = blockIdx.x * blockDim.x + threadIdx.x;
    if (g >= 2 * PP_STRIDE) return;
    int arr = g / PP_STRIDE, u = g % PP_STRIDE;
    unsigned int* p = pp + ((size_t)arr * CHK) * PP_STRIDE + u;
    int s0 = 0, s1 = 0, s2 = 0, s3 = 0;
#pragma unroll 8
    for (int c = 0; c < CHK; c++) {
        unsigned int v = p[(size_t)c * PP_STRIDE];
        p[(size_t)c * PP_STRIDE] =
            (unsigned)s0 | ((unsigned)s1 << 8) | ((unsigned)s2 << 16) | ((unsigned)s3 << 24);
        s0 += v & 255; s1 += (v >> 8) & 255; s2 += (v >> 16) & 255; s3 += (v >> 24) & 255;
    }
    int* cnt = arr ? cnt_dst : cnt_src;
    cnt[4 * u + 0] = s0; cnt[4 * u + 1] = s1; cnt[4 * u + 2] = s2; cnt[4 * u + 3] = s3;
}

// scan both cnt arrays
__global__ __launch_bounds__(1024) void
k_scan1(const int* __restrict__ cnt_dst, const int* __restrict__ cnt_src,
        int* __restrict__ rpD, int* __restrict__ rpS,
        int* __restrict__ bsD, int* __restrict__ bsS) {
    __shared__ int s[1024];
    int arr = blockIdx.x / SCAN_NB, bb = blockIdx.x % SCAN_NB;
    const int* cnt = arr ? cnt_src : cnt_dst;
    int* rp1 = (arr ? rpS : rpD) + 1;
    int* bs = arr ? bsS : bsD;
    int tid = threadIdx.x;
    int i = bb * 1024 + tid;
    int v = (i < N_NODES) ? cnt[i] : 0;
    s[tid] = v;
    __syncthreads();
    for (int d = 1; d < 1024; d <<= 1) {
        int t = (tid >= d) ? s[tid - d] : 0;
        __syncthreads();
        s[tid] += t;
        __syncthreads();
    }
    if (i < N_NODES) rp1[i] = s[tid];
    if (tid == 1023) bs[bb] = s[1023];
}

__global__ void k_scan2(int* __restrict__ bsD, int* __restrict__ bsS) {
    __shared__ int s[128];
    int* bs = blockIdx.x ? bsS : bsD;
    int tid = threadIdx.x;
    int v = (tid < SCAN_NB) ? bs[tid] : 0;
    s[tid] = v;
    __syncthreads();
    for (int d = 1; d < 128; d <<= 1) {
        int t = (tid >= d) ? s[tid - d] : 0;
        __syncthreads();
        s[tid] += t;
        __syncthreads();
    }
    if (tid < SCAN_NB) bs[tid] = s[tid] - v;  // exclusive
}

// finalize both row_ptrs + norms + zero colsum
__global__ void k_scan3norm(int* __restrict__ rpD, int* __restrict__ rpS,
                            const int* __restrict__ bsD, const int* __restrict__ bsS,
                            const int* __restrict__ cnt_src, const int* __restrict__ cnt_dst,
                            float* __restrict__ ns, float* __restrict__ nd,
                            float* __restrict__ colsum) {
    int i = blockIdx.x * blockDim.x + threadIdx.x;
    if (i >= N_NODES) return;
    rpD[1 + i] += bsD[i >> 10];
    rpS[1 + i] += bsS[i >> 10];
    if (i == 0) { rpD[0] = 0; rpS[0] = 0; }
    if (i < 128) colsum[i] = 0.0f;
    ns[i] = rsqrtf((float)max(cnt_src[i], 1));
    nd[i] = rsqrtf((float)max(cnt_dst[i], 1));
}

// Pass C (merged): counting-sort scatters, 512 blocks.
// blocks [0,256):   by dst, payload src        -> csr_src
// blocks [256,512): by src, payload nd[dst]    -> csrv
__global__ __launch_bounds__(256) void
k_scatter_both(const int* __restrict__ src, const int* __restrict__ dst,
               const int* __restrict__ rpD, const int* __restrict__ rpS,
               const unsigned int* __restrict__ pp, const float* __restrict__ nd,
               int* __restrict__ csr_src, float* __restrict__ csrv) {
    __shared__ unsigned int cur[SH2_U];  // 50 KB
    int which = blockIdx.x >> 8;         // 0 = dst-sort, 1 = src-sort
    int bb = blockIdx.x & 255;
    int sh = bb & 1, c = bb >> 1;
    int lo = sh * SH2;
    for (int i = threadIdx.x; i < SH2_U; i += 256) cur[i] = 0;
    __syncthreads();
    int e0 = c * CHUNK_E;
    if (which == 0) {
        const unsigned int* pre = pp + ((size_t)(CHK + c)) * PP_STRIDE;  // arr=1 (dst)
        for (int i = e0 + threadIdx.x; i < e0 + CHUNK_E; i += 256) {
            int dfull = dst[i];
            int d = dfull - lo;
            if ((unsigned)d < SH2) {
                int sft = (d & 3) * 8;
                int rank = (atomicAdd(&cur[d >> 2], 1u << sft) >> sft) & 255;
                int p8 = (pre[dfull >> 2] >> ((dfull & 3) * 8)) & 255;
                csr_src[rpD[dfull] + p8 + rank] = src[i];
            }
        }
    } else {
        const unsigned int* pre = pp + (size_t)c * PP_STRIDE;  // arr=0 (src)
        for (int i = e0 + threadIdx.x; i < e0 + CHUNK_E; i += 256) {
            int sfull = src[i];
            int s = sfull - lo;
            if ((unsigned)s < SH2) {
                int sft = (s & 3) * 8;
                int rank = (atomicAdd(&cur[s >> 2], 1u << sft) >> sft) & 255;
                int p8 = (pre[sfull >> 2] >> ((sfull & 3) * 8)) & 255;
                csrv[rpS[sfull] + p8 + rank] = nd[dst[i]];
            }
        }
    }
}

// wsum[n] = ns[n] * sum of csrv over n's src-list
__global__ void k_wsum(const int* __restrict__ rpS, const float* __restrict__ csrv,
                       const float* __restrict__ ns, float* __restrict__ wsum) {
    int gid = blockIdx.x * blockDim.x + threadIdx.x;
    int wv = gid >> 6, lane = gid & 63;
    int n = wv * 16 + (lane & 15);
    int off = lane >> 4;
    float s = 0.0f;
    int beg = 0, end = 0;
    if (n < N_NODES) { beg = rpS[n]; end = rpS[n + 1]; }
    for (int j = beg + off; j < end; j += 4) s += csrv[j];
    s += __shfl_xor(s, 16, 64);
    s += __shfl_xor(s, 32, 64);
    if (n < N_NODES && lane < 16) wsum[n] = s * ns[n];
}

// fused prep: blocks [0,128): Wt16[l][n][k] = half(Wl[k][n]);
//             blocks [128,...): x8[n][:] = fp8(h[n][:] * ns[n])
__global__ void k_prep(const float* __restrict__ W0, const float* __restrict__ W1,
                       __half* __restrict__ Wt, const float* __restrict__ x,
                       const float* __restrict__ ns, unsigned int* __restrict__ out) {
    if (blockIdx.x < 128) {
        int i = blockIdx.x * 256 + threadIdx.x;  // over 2*D*D
        int l = i >> 14, r = i & (D * D - 1);
        int n = r >> 7, k = r & 127;
        const float* W = l ? W1 : W0;
        Wt[i] = __float2half(W[k * D + n]);
        return;
    }
    int i = (blockIdx.x - 128) * 256 + threadIdx.x;  // over N*D/4
    if (i >= N_NODES * (D / 4)) return;
    int n = i >> 5;
    float4 v = ((const float4*)x)[i];
    float s = ns[n];
    int u = __builtin_amdgcn_cvt_pk_fp8_f32(v.x * s, v.y * s, 0, false);
    u = __builtin_amdgcn_cvt_pk_fp8_f32(v.z * s, v.w * s, u, true);
    out[i] = (unsigned int)u;
}

// pull SpMM (fp8 gather -> fp32 accum -> fp16 agg): one wave per node,
// 2 edges per gather instruction (lane reads uint = 4 fp8; 32 lanes/row).
__global__ __launch_bounds__(256) void
k_spmm(const unsigned char* __restrict__ x8, const int* __restrict__ row_ptr,
       const int* __restrict__ csr_src, __half* __restrict__ agg) {
    int wave = (blockIdx.x * blockDim.x + threadIdx.x) >> 6;
    int lane = threadIdx.x & 63;
    int hf = lane >> 5, l32 = lane & 31;
    if (wave >= N_NODES) return;
    int beg = row_ptr[wave], end = row_ptr[wave + 1];
    float a0 = 0.f, a1 = 0.f, a2 = 0.f, a3 = 0.f;
    int j = beg;
    for (; j + 7 < end; j += 8) {
#pragma unroll
        for (int p = 0; p < 4; p++) {
            int s0 = csr_src[j + 2 * p];
            int s1 = csr_src[j + 2 * p + 1];
            int s = hf ? s1 : s0;
            unsigned int u = *(const unsigned int*)(x8 + (size_t)s * D + 4 * l32);
            f32x2 lo = __builtin_amdgcn_cvt_pk_f32_fp8(u, false);
            f32x2 hi = __builtin_amdgcn_cvt_pk_f32_fp8(u, true);
            a0 += lo[0]; a1 += lo[1]; a2 += hi[0]; a3 += hi[1];
        }
    }
    for (; j + 1 < end; j += 2) {
        int s0 = csr_src[j], s1 = csr_src[j + 1];
        int s = hf ? s1 : s0;
        unsigned int u = *(const unsigned int*)(x8 + (size_t)s * D + 4 * l32);
        f32x2 lo = __builtin_amdgcn_cvt_pk_f32_fp8(u, false);
        f32x2 hi = __builtin_amdgcn_cvt_pk_f32_fp8(u, true);
        a0 += lo[0]; a1 += lo[1]; a2 += hi[0]; a3 += hi[1];
    }
    if (j < end && hf == 0) {
        int s = csr_src[j];
        unsigned int u = *(const unsigned int*)(x8 + (size_t)s * D + 4 * l32);
        f32x2 lo = __builtin_amdgcn_cvt_pk_f32_fp8(u, false);
        f32x2 hi = __builtin_amdgcn_cvt_pk_f32_fp8(u, true);
        a0 += lo[0]; a1 += lo[1]; a2 += hi[0]; a3 += hi[1];
    }
    a0 += __shfl_xor(a0, 32, 64);
    a1 += __shfl_xor(a1, 32, 64);
    a2 += __shfl_xor(a2, 32, 64);
    a3 += __shfl_xor(a3, 32, 64);
    if (hf == 0) {
        f16x4 o;
        o[0] = (_Float16)a0; o[1] = (_Float16)a1; o[2] = (_Float16)a2; o[3] = (_Float16)a3;
        ((f16x4*)(agg + (size_t)wave * D))[l32] = o;
    }
}

// MFMA GEMM (layer 0): A fp16 (agg), out fp8 rows (pre-scaled by ns).
__global__ __launch_bounds__(256) void
k_gemm_mfma(const __half* __restrict__ A, const __half* __restrict__ Wt,
            const float* __restrict__ b, const float* __restrict__ nd,
            const float* __restrict__ ns, unsigned char* __restrict__ out) {
    int w = threadIdx.x >> 6, lane = threadIdx.x & 63;
    int m = lane & 15, q = lane >> 4;
    int row0 = blockIdx.x * 128 + w * 32;

    f16x8 zf;
#pragma unroll
    for (int j = 0; j < 8; j++) zf[j] = (_Float16)0;
    f16x8 af[2][4];
#pragma unroll
    for (int g = 0; g < 2; g++) {
        int arow = row0 + g * 16 + m;
        const f16x8* pa = (const f16x8*)(A + (size_t)arow * D);
        bool aok = arow < N_NODES;
#pragma unroll
        for (int ks = 0; ks < 4; ks++) af[g][ks] = aok ? pa[ks * 4 + q] : zf;
    }

    const f16x8* pb = (const f16x8*)Wt;
    f32x4 acc[2][8];
#pragma unroll
    for (int g = 0; g < 2; g++)
#pragma unroll
        for (int nt = 0; nt < 8; nt++) acc[g][nt] = (f32x4){0.f, 0.f, 0.f, 0.f};

#pragma unroll
    for (int ks = 0; ks < 4; ks++) {
#pragma unroll
        for (int nt = 0; nt < 8; nt++) {
            f16x8 bf = pb[((nt * 16 + m) << 4) + (ks << 2) + q];
            acc[0][nt] = __builtin_amdgcn_mfma_f32_16x16x32_f16(af[0][ks], bf, acc[0][nt], 0, 0, 0);
            acc[1][nt] = __builtin_amdgcn_mfma_f32_16x16x32_f16(af[1][ks], bf, acc[1][nt], 0, 0, 0);
        }
    }

#pragma unroll
    for (int g = 0; g < 2; g++) {
        int er = row0 + g * 16 + q * 4;
        float sd[4], ss[4];
#pragma unroll
        for (int r = 0; r < 4; r++) {
            int n = er + r;
            bool ok = n < N_NODES;
            sd[r] = ok ? nd[n] : 0.0f;
            ss[r] = ok ? ns[n] : 0.0f;
        }
#pragma unroll
        for (int nt = 0; nt < 8; nt++) {
            int col = nt * 16 + m;
            float bc = b[col];
#pragma unroll
            for (int r = 0; r < 4; r++) {
                int n = er + r;
                if (n < N_NODES) {
                    float v = fmaxf(sd[r] * acc[g][nt][r] + bc, 0.0f) * ss[r];
                    int pk = __builtin_amdgcn_cvt_pk_fp8_f32(v, v, 0, false);
                    out[(size_t)n * D + col] = (unsigned char)(pk & 0xff);
                }
            }
        }
    }
}

// MFMA GEMM (layer 1 + fused final reduction):
// colsum[col] += sum_n wsum[n] * relu(nd[n]*(A@W1)[n][col] + b1[col])
__global__ __launch_bounds__(256) void
k_gemm_red(const __half* __restrict__ A, const __half* __restrict__ Wt,
           const float* __restrict__ b, const float* __restrict__ nd,
           const float* __restrict__ wsum, float* __restrict__ colsum) {
    __shared__ float red[128];
    int tid = threadIdx.x;
    if (tid < 128) red[tid] = 0.0f;
    __syncthreads();

    int w = tid >> 6, lane = tid & 63;
    int m = lane & 15, q = lane >> 4;
    int row0 = blockIdx.x * 128 + w * 32;

    f16x8 zf;
#pragma unroll
    for (int j = 0; j < 8; j++) zf[j] = (_Float16)0;
    f16x8 af[2][4];
#pragma unroll
    for (int g = 0; g < 2; g++) {
        int arow = row0 + g * 16 + m;
        const f16x8* pa = (const f16x8*)(A + (size_t)arow * D);
        bool aok = arow < N_NODES;
#pragma unroll
        for (int ks = 0; ks < 4; ks++) af[g][ks] = aok ? pa[ks * 4 + q] : zf;
    }

    const f16x8* pb = (const f16x8*)Wt;
    f32x4 acc[2][8];
#pragma unroll
    for (int g = 0; g < 2; g++)
#pragma unroll
        for (int nt = 0; nt < 8; nt++) acc[g][nt] = (f32x4){0.f, 0.f, 0.f, 0.f};

#pragma unroll
    for (int ks = 0; ks < 4; ks++) {
#pragma unroll
        for (int nt = 0; nt < 8; nt++) {
            f16x8 bf = pb[((nt * 16 + m) << 4) + (ks << 2) + q];
            acc[0][nt] = __builtin_amdgcn_mfma_f32_16x16x32_f16(af[0][ks], bf, acc[0][nt], 0, 0, 0);
            acc[1][nt] = __builtin_amdgcn_mfma_f32_16x16x32_f16(af[1][ks], bf, acc[1][nt], 0, 0, 0);
        }
    }

    float sd[2][4], sw[2][4];
#pragma unroll
    for (int g = 0; g < 2; g++) {
        int er = row0 + g * 16 + q * 4;
#pragma unroll
        for (int r = 0; r < 4; r++) {
            int n = er + r;
            bool ok = n < N_NODES;
            sd[g][r] = ok ? nd[n] : 0.0f;
            sw[g][r] = ok ? wsum[n] : 0.0f;
        }
    }
#pragma unroll
    for (int nt = 0; nt < 8; nt++) {
        int col = nt * 16 + m;
        float bc = b[col];
        float pc = 0.0f;
#pragma unroll
        for (int g = 0; g < 2; g++)
#pragma unroll
            for (int r = 0; r < 4; r++)
                pc += sw[g][r] * fmaxf(sd[g][r] * acc[g][nt][r] + bc, 0.0f);
        atomicAdd(&red[col], pc);
    }
    __syncthreads();
    if (tid < 128) unsafeAtomicAdd(&colsum[tid], red[tid]);
}

// out[j] = (colsum/N) @ W2 [:,j] + b2[j]
__global__ void k_final(const float* __restrict__ colsum, const float* __restrict__ W,
                        const float* __restrict__ b, float* __restrict__ out) {
    __shared__ float m[128];
    int j = threadIdx.x;
    m[j] = colsum[j] * (1.0f / N_NODES);
    __syncthreads();
    float acc = b[j];
    for (int k = 0; k < 128; k++)
        acc = fmaf(m[k], W[(size_t)k * D + j], acc);
    out[j] = acc;
}

extern "C" void kernel_launch(void* const* d_in, const int* in_sizes, int n_in,
                              void* d_out, int out_size, void* d_ws, size_t ws_size,
                              hipStream_t stream) {
    const float* h   = (const float*)d_in[0];
    const int*   src = (const int*)d_in[1];
    const int*   dst = (const int*)d_in[2];
    const float* W0  = (const float*)d_in[3];
    const float* b0  = (const float*)d_in[4];
    const float* W1  = (const float*)d_in[5];
    const float* b1  = (const float*)d_in[6];
    const float* W2  = (const float*)d_in[7];
    const float* b2  = (const float*)d_in[8];
    float* out = (float*)d_out;

    // workspace (~70 MB); pp (25.6 MB) dead after scatters -> x8 (12.8 MB) aliases it
    float*         ns      = (float*)d_ws;                       // N
    float*         nd      = ns + N_NODES;                       // N
    float*         wsum    = nd + N_NODES;                       // N
    float*         colsum  = wsum + N_NODES;                     // 128
    int*           rpD     = (int*)(colsum + 128);               // N+1
    int*           rpS     = rpD + N_NODES + 1;                  // N+1
    int*           cnt_src = rpS + N_NODES + 1;                  // N
    int*           cnt_dst = cnt_src + N_NODES;                  // N
    int*           bsD     = cnt_dst + N_NODES;                  // 128
    int*           bsS     = bsD + 128;                          // 128
    __half*        Wt16    = (__half*)(bsS + 128);               // 2*D*D
    int*           csr_src = (int*)(Wt16 + 2 * D * D);           // E
    float*         csrv    = (float*)(csr_src + N_EDGES);        // E
    unsigned int*  pp      = (unsigned int*)(csrv + N_EDGES);    // 25.6 MB
    unsigned char* x8      = (unsigned char*)pp;                 // N*D fp8 (12.8 MB, aliases pp)
    __half*        agg16   = (__half*)(pp + 2 * (size_t)CHK * PP_STRIDE); // N*D fp16

    // ---- CSR build (both directions) + norms + wsum; no global atomics ----
    k_hist<<<2 * 2 * CHK, 256, 0, stream>>>(src, dst, pp);
    k_merge<<<(2 * PP_STRIDE + 255) / 256, 256, 0, stream>>>(pp, cnt_src, cnt_dst);
    k_scan1<<<2 * SCAN_NB, 1024, 0, stream>>>(cnt_dst, cnt_src, rpD, rpS, bsD, bsS);
    k_scan2<<<2, 128, 0, stream>>>(bsD, bsS);
    k_scan3norm<<<(N_NODES + 255) / 256, 256, 0, stream>>>(rpD, rpS, bsD, bsS,
                                                           cnt_src, cnt_dst, ns, nd, colsum);
    k_scatter_both<<<2 * NSH2 * CHK, 256, 0, stream>>>(src, dst, rpD, rpS, pp, nd,
                                                       csr_src, csrv);
    k_wsum<<<(N_NODES * 4 + 255) / 256, 256, 0, stream>>>(rpS, csrv, ns, wsum);

    // Wt + x0 = fp8(h*ns)  (x8 overwrites pp region — stream-ordered after scatters)
    k_prep<<<128 + (N_NODES * (D / 4) + 255) / 256, 256, 0, stream>>>(
        W0, W1, Wt16, h, ns, (unsigned int*)x8);

    // layer 0
    k_spmm<<<(N_NODES + 3) / 4, 256, 0, stream>>>(x8, rpD, csr_src, agg16);
    k_gemm_mfma<<<(N_NODES + 127) / 128, 256, 0, stream>>>(agg16, Wt16, b0, nd, ns, x8);
    // layer 1 + fused layer-2 reduction
    k_spmm<<<(N_NODES + 3) / 4, 256, 0, stream>>>(x8, rpD, csr_src, agg16);
    k_gemm_red<<<(N_NODES + 127) / 128, 256, 0, stream>>>(agg16, Wt16 + (size_t)D * D,
                                                          b1, nd, wsum, colsum);
    k_final<<<1, 128, 0, stream>>>(colsum, W2, b2, out);
}